// Round 1
// baseline (334.238 us; speedup 1.0000x reference)
//
#include <hip/hip_runtime.h>
#include <hip/hip_bf16.h>
#include <math.h>

#define BATCH   2
#define SEQ     4096
#define DIM     1024
#define HEADS   16
#define DSTATE  64
#define HEADDIM 64
#define BLOCKL  64
#define NCHUNK  64          // SEQ / BLOCKL
#define ROWS    (BATCH*SEQ) // 8192

typedef __attribute__((ext_vector_type(4))) float f32x4;
typedef __attribute__((ext_vector_type(8))) short bf16x8;

static __device__ __forceinline__ float softplus_f(float x){
    return (x > 20.f) ? x : log1pf(__expf(x));
}

// ---------------------------------------------------------------------------
// K1: dt[b,s,h] = softplus(X[b,s,:] @ W_dt[:,h] + dt_bias[s,h]);  dtA = -exp(a_log[h])*dt
// one block per row (b,s)
__global__ __launch_bounds__(256) void k_dt(const float* __restrict__ X,
        const float* __restrict__ Wdt, const float* __restrict__ dtb,
        const float* __restrict__ alog,
        float* __restrict__ dt_g, float* __restrict__ dtA_g){
    int r = blockIdx.x;           // 0..8191
    int s = r & (SEQ-1);
    int tid = threadIdx.x;
    __shared__ float xrow[DIM];
    __shared__ float red[16][17];
    *(f32x4*)(xrow + tid*4) = *(const f32x4*)(X + (size_t)r*DIM + tid*4);
    __syncthreads();
    int part = tid >> 4, h = tid & 15;
    int d0 = part * 64;
    float acc = 0.f;
    #pragma unroll 8
    for (int i = 0; i < 64; ++i)
        acc += xrow[d0 + i] * Wdt[(size_t)(d0 + i)*HEADS + h];
    red[part][h] = acc;
    __syncthreads();
    if (tid < 16){
        float sum = 0.f;
        #pragma unroll
        for (int p = 0; p < 16; ++p) sum += red[p][tid];
        sum += dtb[(size_t)s*HEADS + tid];
        float dtv = softplus_f(sum);
        dt_g[(size_t)r*HEADS + tid]  = dtv;
        dtA_g[(size_t)r*HEADS + tid] = -__expf(alog[tid]) * dtv;
    }
}

// ---------------------------------------------------------------------------
// K2: per (b,c,h): Y_diag, chunk_state, store cumsum
__global__ __launch_bounds__(256) void k_chunk(const float* __restrict__ X,
        const float* __restrict__ Bin, const float* __restrict__ Cin,
        const float* __restrict__ dt_g, const float* __restrict__ dtA_g,
        float* __restrict__ y_g, float* __restrict__ cstate, float* __restrict__ css_g){
    int bid = blockIdx.x;                  // ((b*64+c)*16+h)
    int h = bid & 15, c = (bid >> 4) & 63, b = bid >> 10;
    int tid = threadIdx.x;
    int r0 = b*SEQ + c*BLOCKL;
    __shared__ float Xs[64][65], Bs[64][65], Cs[64][65];
    __shared__ float csh[64], dtsh[64], wsh[64];

    int l  = tid >> 2;
    int c0 = (tid & 3) * 16;
    {
        const float* xp = X   + (size_t)(r0 + l)*DIM + h*HEADDIM + c0;
        const float* bp = Bin + (size_t)(r0 + l)*DIM + h*DSTATE  + c0;
        const float* cp = Cin + (size_t)(r0 + l)*DIM + h*DSTATE  + c0;
        #pragma unroll
        for (int q = 0; q < 4; ++q){
            *(f32x4*)&Xs[l][c0+q*4] = *(const f32x4*)(xp + q*4);
            *(f32x4*)&Bs[l][c0+q*4] = *(const f32x4*)(bp + q*4);
            *(f32x4*)&Cs[l][c0+q*4] = *(const f32x4*)(cp + q*4);
        }
    }
    if (tid < 64){
        dtsh[tid] = dt_g[(size_t)(r0 + tid)*HEADS + h];
        float a = dtA_g[(size_t)(r0 + tid)*HEADS + h];
        #pragma unroll
        for (int off = 1; off < 64; off <<= 1){       // inclusive wave scan
            float v = __shfl_up(a, off, 64);
            if (tid >= off) a += v;
        }
        csh[tid] = a;
    }
    __syncthreads();
    // scale X rows by dt (Xd = X*dt), decay weights
    {
        float dl = dtsh[l];
        #pragma unroll
        for (int j = 0; j < 16; ++j) Xs[l][c0+j] *= dl;
    }
    if (tid < 64){
        wsh[tid] = __expf(csh[63] - csh[tid]);
        css_g[(size_t)bid*64 + tid] = csh[tid];
    }
    __syncthreads();
    // M[l][s] = (s<=l) ? (C[l]·B[s]) * exp(cs[l]-cs[s]) : 0   (into regs, then reuse Cs)
    float mreg[16];
    {
        float cl = csh[l];
        #pragma unroll 2
        for (int js = 0; js < 16; ++js){
            int s = c0 + js;
            float g = 0.f;
            #pragma unroll 8
            for (int n = 0; n < 64; ++n) g += Cs[l][n]*Bs[s][n];
            mreg[js] = (s <= l) ? g * __expf(cl - csh[s]) : 0.f;
        }
    }
    __syncthreads();
    #pragma unroll
    for (int js = 0; js < 16; ++js) Cs[l][c0+js] = mreg[js];   // Cs now holds M
    __syncthreads();
    // Y_diag[l][p] = sum_s M[l][s] * Xd[s][p]
    {
        float acc[16];
        #pragma unroll
        for (int j = 0; j < 16; ++j) acc[j] = 0.f;
        for (int s = 0; s < 64; ++s){
            float m = Cs[l][s];
            #pragma unroll
            for (int j = 0; j < 16; ++j) acc[j] += m * Xs[s][c0+j];
        }
        float* yp = y_g + (size_t)(r0 + l)*DIM + h*HEADDIM + c0;
        #pragma unroll
        for (int j = 0; j < 16; ++j) yp[j] = acc[j];
    }
    // chunk_state[p][n] = sum_l w[l] * Xd[l][p] * B[l][n]
    {
        int p  = tid >> 2;
        int n0 = (tid & 3) * 16;
        float acc[16];
        #pragma unroll
        for (int j = 0; j < 16; ++j) acc[j] = 0.f;
        for (int ll = 0; ll < 64; ++ll){
            float wx = wsh[ll] * Xs[ll][p];
            #pragma unroll
            for (int j = 0; j < 16; ++j) acc[j] += wx * Bs[ll][n0+j];
        }
        float* sp = cstate + (size_t)bid*4096 + p*64 + n0;
        #pragma unroll
        for (int j = 0; j < 16; ++j) sp[j] = acc[j];
    }
}

// ---------------------------------------------------------------------------
// K3: inter-chunk scan (in place: chunk_state -> states_in), emit final_state
__global__ __launch_bounds__(256) void k_scan(float* __restrict__ cstate,
        const float* __restrict__ css_g, float* __restrict__ fs_out){
    int bid = blockIdx.x;                  // b(2) * h(16) * tile(16)
    int tile = bid & 15, h = (bid >> 4) & 15, b = bid >> 8;
    int pn = tile*256 + threadIdx.x;
    float P = 0.f;
    for (int c = 0; c < NCHUNK; ++c){
        size_t base = (size_t)((b*NCHUNK + c)*HEADS + h);
        float e   = __expf(css_g[base*64 + 63]);
        float cur = cstate[base*4096 + pn];
        cstate[base*4096 + pn] = P;        // states_in for chunk c
        P = e*P + cur;
    }
    fs_out[(size_t)(b*HEADS + h)*4096 + pn] = P;
}

// ---------------------------------------------------------------------------
// K4: Y_off[l][p] = exp(cs[l]) * sum_n C[l][n] * S[p][n];  y += Y_off
__global__ __launch_bounds__(256) void k_yoff(const float* __restrict__ Cin,
        const float* __restrict__ cstate, const float* __restrict__ css_g,
        float* __restrict__ y_g){
    int bid = blockIdx.x;
    int h = bid & 15, c = (bid >> 4) & 63, b = bid >> 10;
    int tid = threadIdx.x;
    int r0 = b*SEQ + c*BLOCKL;
    __shared__ float Ss[64][65], Cs[64][65], cse[64];
    int l  = tid >> 2;
    int c0 = (tid & 3) * 16;
    {
        const float* cp = Cin    + (size_t)(r0 + l)*DIM + h*DSTATE + c0;
        const float* sp = cstate + (size_t)bid*4096 + l*64 + c0;
        #pragma unroll
        for (int q = 0; q < 4; ++q){
            *(f32x4*)&Cs[l][c0+q*4] = *(const f32x4*)(cp + q*4);
            *(f32x4*)&Ss[l][c0+q*4] = *(const f32x4*)(sp + q*4);
        }
    }
    if (tid < 64) cse[tid] = __expf(css_g[(size_t)bid*64 + tid]);
    __syncthreads();
    float acc[16];
    #pragma unroll
    for (int j = 0; j < 16; ++j) acc[j] = 0.f;
    for (int n = 0; n < 64; ++n){
        float cl = Cs[l][n];
        #pragma unroll
        for (int j = 0; j < 16; ++j) acc[j] += cl * Ss[c0+j][n];
    }
    float e = cse[l];
    float* yp = y_g + (size_t)(r0 + l)*DIM + h*HEADDIM + c0;
    #pragma unroll
    for (int j = 0; j < 16; ++j) yp[j] += e * acc[j];
}

// ---------------------------------------------------------------------------
// K5: LayerNorm over dim, write bf16 yn
__global__ __launch_bounds__(256) void k_ln(const float* __restrict__ y_g,
        const float* __restrict__ scale, const float* __restrict__ bias,
        __hip_bfloat16* __restrict__ yn){
    int r = blockIdx.x, tid = threadIdx.x;
    const float* yp = y_g + (size_t)r*DIM;
    f32x4 v = *(const f32x4*)(yp + tid*4);
    float s1 = v.x + v.y + v.z + v.w;
    float s2 = v.x*v.x + v.y*v.y + v.z*v.z + v.w*v.w;
    #pragma unroll
    for (int m = 32; m > 0; m >>= 1){
        s1 += __shfl_xor(s1, m, 64);
        s2 += __shfl_xor(s2, m, 64);
    }
    __shared__ float w1[4], w2[4];
    int wv = tid >> 6;
    if ((tid & 63) == 0){ w1[wv] = s1; w2[wv] = s2; }
    __syncthreads();
    float S1 = w1[0]+w1[1]+w1[2]+w1[3];
    float S2 = w2[0]+w2[1]+w2[2]+w2[3];
    float mu  = S1 * (1.f/DIM);
    float var = S2 * (1.f/DIM) - mu*mu;
    float rstd = rsqrtf(var + 1e-6f);
    int d = tid*4;
    f32x4 sc = *(const f32x4*)(scale + d);
    f32x4 bi = *(const f32x4*)(bias + d);
    union { __hip_bfloat16 h[4]; short4 s4; } u;
    u.h[0] = __float2bfloat16((v.x - mu)*rstd*sc.x + bi.x);
    u.h[1] = __float2bfloat16((v.y - mu)*rstd*sc.y + bi.y);
    u.h[2] = __float2bfloat16((v.z - mu)*rstd*sc.z + bi.z);
    u.h[3] = __float2bfloat16((v.w - mu)*rstd*sc.w + bi.w);
    *(short4*)((short*)yn + (size_t)r*DIM + d) = u.s4;
}

// ---------------------------------------------------------------------------
// K5b: Wt[n][k] = bf16(W_out[k][n])
__global__ __launch_bounds__(256) void k_wt(const float* __restrict__ W,
        __hip_bfloat16* __restrict__ Wt){
    __shared__ float t[64][65];
    int kt = blockIdx.x >> 4, nt = blockIdx.x & 15;
    int tid = threadIdx.x;
    int lr = tid >> 4, lc4 = (tid & 15) * 4;
    #pragma unroll
    for (int q = 0; q < 4; ++q){
        int k = lr + q*16;
        *(f32x4*)&t[k][lc4] = *(const f32x4*)(W + (size_t)(kt*64 + k)*DIM + nt*64 + lc4);
    }
    __syncthreads();
    #pragma unroll
    for (int q = 0; q < 4; ++q){
        int n = lr + q*16;
        union { __hip_bfloat16 h[4]; short4 s4; } u;
        #pragma unroll
        for (int j = 0; j < 4; ++j) u.h[j] = __float2bfloat16(t[lc4+j][n]);
        *(short4*)((short*)Wt + (size_t)(nt*64 + n)*DIM + kt*64 + lc4) = u.s4;
    }
}

// ---------------------------------------------------------------------------
// K6: Out[m][n] = sum_k yn[m][k] * Wt[n][k]   (bf16 MFMA, f32 accum)
// 128x128 tile, 4 waves (2x2), each wave 64x64 = 4x4 frags of 16x16x32
__global__ __launch_bounds__(256) void k_gemm(const __hip_bfloat16* __restrict__ A,
        const __hip_bfloat16* __restrict__ Bt, float* __restrict__ Out){
    __shared__ ushort As[128*32];
    __shared__ ushort Bsh[128*32];
    int bid = blockIdx.x;
    int bn = bid & 7, bm = bid >> 3;           // N/128 = 8, M/128 = 64
    int tid = threadIdx.x;
    int lane = tid & 63, wave = tid >> 6;
    int wr = wave >> 1, wc = wave & 1;
    f32x4 acc[4][4];
    #pragma unroll
    for (int i = 0; i < 4; ++i)
        #pragma unroll
        for (int j = 0; j < 4; ++j)
            acc[i][j] = (f32x4){0.f, 0.f, 0.f, 0.f};
    const ushort* Ag = (const ushort*)A  + (size_t)bm*128*1024;
    const ushort* Bg = (const ushort*)Bt + (size_t)bn*128*1024;
    int row0 = tid >> 2;
    int col0 = (tid & 3) * 8;
    for (int k0 = 0; k0 < 1024; k0 += 32){
        #pragma unroll
        for (int pass = 0; pass < 2; ++pass){
            int row = row0 + pass*64;
            *(uint4*)&As[row*32 + col0]  = *(const uint4*)(Ag + (size_t)row*1024 + k0 + col0);
            *(uint4*)&Bsh[row*32 + col0] = *(const uint4*)(Bg + (size_t)row*1024 + k0 + col0);
        }
        __syncthreads();
        bf16x8 af[4], bfr[4];
        #pragma unroll
        for (int i = 0; i < 4; ++i){
            int arow = wr*64 + i*16 + (lane & 15);
            af[i] = *(const bf16x8*)&As[arow*32 + ((lane >> 4) << 3)];
        }
        #pragma unroll
        for (int j = 0; j < 4; ++j){
            int brow = wc*64 + j*16 + (lane & 15);
            bfr[j] = *(const bf16x8*)&Bsh[brow*32 + ((lane >> 4) << 3)];
        }
        #pragma unroll
        for (int i = 0; i < 4; ++i)
            #pragma unroll
            for (int j = 0; j < 4; ++j)
                acc[i][j] = __builtin_amdgcn_mfma_f32_16x16x32_bf16(af[i], bfr[j], acc[i][j], 0, 0, 0);
        __syncthreads();
    }
    #pragma unroll
    for (int i = 0; i < 4; ++i){
        int m0 = bm*128 + wr*64 + i*16 + ((lane >> 4) << 2);
        #pragma unroll
        for (int j = 0; j < 4; ++j){
            int n = bn*128 + wc*64 + j*16 + (lane & 15);
            #pragma unroll
            for (int reg = 0; reg < 4; ++reg)
                Out[(size_t)(m0 + reg)*1024 + n] = acc[i][j][reg];
        }
    }
}

// ---------------------------------------------------------------------------
extern "C" void kernel_launch(void* const* d_in, const int* in_sizes, int n_in,
                              void* d_out, int out_size, void* d_ws, size_t ws_size,
                              hipStream_t stream){
    const float* X    = (const float*)d_in[0];
    const float* Bin  = (const float*)d_in[1];
    const float* Cin  = (const float*)d_in[2];
    const float* Wdt  = (const float*)d_in[3];
    const float* dtb  = (const float*)d_in[4];
    const float* alog = (const float*)d_in[5];
    const float* Wout = (const float*)d_in[6];
    const float* lns  = (const float*)d_in[7];
    const float* lnb  = (const float*)d_in[8];

    float* out = (float*)d_out;
    float* y_g = out;                       // reuse out region as y buffer
    float* fs_out = out + (size_t)ROWS*DIM; // final_state region

    float* dt_g   = (float*)d_ws;                       // 131072 f32
    float* dtA_g  = dt_g  + 131072;                     // 131072 f32
    float* css_g  = dtA_g + 131072;                     // 131072 f32
    float* cstate = css_g + 131072;                     // 8388608 f32
    __hip_bfloat16* yn = (__hip_bfloat16*)(cstate + 8388608);  // 8388608 bf16
    __hip_bfloat16* Wt = yn + (size_t)ROWS*DIM;                // 1048576 bf16

    k_dt   <<<ROWS,          256, 0, stream>>>(X, Wdt, dtb, alog, dt_g, dtA_g);
    k_chunk<<<BATCH*NCHUNK*HEADS, 256, 0, stream>>>(X, Bin, Cin, dt_g, dtA_g, y_g, cstate, css_g);
    k_scan <<<BATCH*HEADS*16, 256, 0, stream>>>(cstate, css_g, fs_out);
    k_yoff <<<BATCH*NCHUNK*HEADS, 256, 0, stream>>>(Cin, cstate, css_g, y_g);
    k_ln   <<<ROWS,          256, 0, stream>>>(y_g, lns, lnb, yn);
    k_wt   <<<256,           256, 0, stream>>>(Wout, Wt);
    k_gemm <<<512,           256, 0, stream>>>(yn, Wt, out);
}

// Round 2
// 137.357 us; speedup vs baseline: 2.4333x; 2.4333x over previous
//
#include <hip/hip_runtime.h>
#include <hip/hip_bf16.h>
#include <math.h>

#define BATCH   2
#define SEQ     4096
#define DIM     1024
#define HEADS   16
#define DSTATE  64
#define HEADDIM 64
#define BLOCKL  64
#define NCHUNK  64          // SEQ / BLOCKL
#define ROWS    (BATCH*SEQ) // 8192

typedef __attribute__((ext_vector_type(4))) float f32x4;
typedef __attribute__((ext_vector_type(8))) short bf16x8;

static __device__ __forceinline__ float softplus_f(float x){
    return (x > 20.f) ? x : log1pf(__expf(x));
}
static __device__ __forceinline__ ushort f2b(float f){
    __hip_bfloat16 h = __float2bfloat16(f);
    return *reinterpret_cast<ushort*>(&h);
}

// ---------------------------------------------------------------------------
// K1: dt[b,s,h] = softplus(X[b,s,:] @ W_dt[:,h] + dt_bias[s,h]);  dtA = -exp(a_log[h])*dt
__global__ __launch_bounds__(256) void k_dt(const float* __restrict__ X,
        const float* __restrict__ Wdt, const float* __restrict__ dtb,
        const float* __restrict__ alog,
        float* __restrict__ dt_g, float* __restrict__ dtA_g){
    int r = blockIdx.x;           // 0..8191
    int s = r & (SEQ-1);
    int tid = threadIdx.x;
    __shared__ float xrow[DIM];
    __shared__ float red[16][17];
    *(f32x4*)(xrow + tid*4) = *(const f32x4*)(X + (size_t)r*DIM + tid*4);
    __syncthreads();
    int part = tid >> 4, h = tid & 15;
    int d0 = part * 64;
    float acc = 0.f;
    #pragma unroll 8
    for (int i = 0; i < 64; ++i)
        acc += xrow[d0 + i] * Wdt[(size_t)(d0 + i)*HEADS + h];
    red[part][h] = acc;
    __syncthreads();
    if (tid < 16){
        float sum = 0.f;
        #pragma unroll
        for (int p = 0; p < 16; ++p) sum += red[p][tid];
        sum += dtb[(size_t)s*HEADS + tid];
        float dtv = softplus_f(sum);
        dt_g[(size_t)r*HEADS + tid]  = dtv;
        dtA_g[(size_t)r*HEADS + tid] = -__expf(alog[tid]) * dtv;
    }
}

// ---------------------------------------------------------------------------
// K2 (MFMA): per (b,c,h): G=C·B^T -> M (mask*decay, f32 LDS) ; Y_diag=M·Xd ;
//            chunk_state = (w*Xd)^T·B.  All matmuls via mfma_f32_16x16x32_bf16.
__global__ __launch_bounds__(256) void k_chunk(const float* __restrict__ X,
        const float* __restrict__ Bin, const float* __restrict__ Cin,
        const float* __restrict__ dt_g, const float* __restrict__ dtA_g,
        float* __restrict__ y_g, float* __restrict__ cstate, float* __restrict__ css_g){
    int bid = blockIdx.x;                  // ((b*64+c)*16+h)
    int h = bid & 15, c = (bid >> 4) & 63, b = bid >> 10;
    int tid = threadIdx.x;
    int lane = tid & 63, wave = tid >> 6;
    int r0 = b*SEQ + c*BLOCKL;

    // LDS: region0 holds Cs+Bs (bf16, stride 72), reused as M (f32, stride 65)
    __shared__ __align__(16) char region0[2*64*72*2];   // 18432 B
    __shared__ __align__(16) ushort XdT [64*72];        // Xd^T  [p][l]
    __shared__ __align__(16) ushort WXdT[64*72];        // (w*Xd)^T [p][l]
    __shared__ __align__(16) ushort BT  [64*72];        // B^T   [n][l]
    __shared__ float csh[64], dtsh[64], wsh[64];
    ushort* Cs = (ushort*)region0;            // [64][72]
    ushort* Bs = (ushort*)(region0 + 9216);   // [64][72]
    float*  Mf = (float*)region0;             // [64][65] (after G)

    // ---- phase 1: cumsum scan (wave 0) + row-major staging of C, B -------
    if (tid < 64){
        dtsh[tid] = dt_g[(size_t)(r0 + tid)*HEADS + h];
        float a = dtA_g[(size_t)(r0 + tid)*HEADS + h];
        #pragma unroll
        for (int off = 1; off < 64; off <<= 1){       // inclusive wave scan
            float v = __shfl_up(a, off, 64);
            if (tid >= off) a += v;
        }
        csh[tid] = a;
        css_g[(size_t)bid*64 + tid] = a;
    }
    {
        int l  = tid >> 2;
        int c0 = (tid & 3) * 16;
        const float* bp = Bin + (size_t)(r0 + l)*DIM + h*DSTATE + c0;
        const float* cp = Cin + (size_t)(r0 + l)*DIM + h*DSTATE + c0;
        ushort tb[16], tc[16];
        #pragma unroll
        for (int q = 0; q < 4; ++q){
            f32x4 vb = *(const f32x4*)(bp + q*4);
            f32x4 vc = *(const f32x4*)(cp + q*4);
            #pragma unroll
            for (int j = 0; j < 4; ++j){ tb[q*4+j] = f2b(vb[j]); tc[q*4+j] = f2b(vc[j]); }
        }
        *(uint4*)&Bs[l*72 + c0]     = *(uint4*)&tb[0];
        *(uint4*)&Bs[l*72 + c0 + 8] = *(uint4*)&tb[8];
        *(uint4*)&Cs[l*72 + c0]     = *(uint4*)&tc[0];
        *(uint4*)&Cs[l*72 + c0 + 8] = *(uint4*)&tc[8];
    }
    __syncthreads();
    if (tid < 64) wsh[tid] = __expf(csh[63] - csh[tid]);
    __syncthreads();

    // ---- phase 2: column staging of XdT, WXdT, BT (transposed, l-contig) --
    {
        int p  = tid >> 2;           // row of transposed buffers
        int l0 = (tid & 3) * 16;
        const float* xcol = X   + (size_t)r0*DIM + h*HEADDIM + p;
        const float* bcol = Bin + (size_t)r0*DIM + h*DSTATE  + p;
        ushort tx[16], tw[16], tbt[16];
        #pragma unroll
        for (int i = 0; i < 16; ++i){
            int l = l0 + i;
            float xv = xcol[(size_t)l*DIM] * dtsh[l];
            tx[i]  = f2b(xv);
            tw[i]  = f2b(xv * wsh[l]);
            tbt[i] = f2b(bcol[(size_t)l*DIM]);
        }
        *(uint4*)&XdT [p*72 + l0]     = *(uint4*)&tx[0];
        *(uint4*)&XdT [p*72 + l0 + 8] = *(uint4*)&tx[8];
        *(uint4*)&WXdT[p*72 + l0]     = *(uint4*)&tw[0];
        *(uint4*)&WXdT[p*72 + l0 + 8] = *(uint4*)&tw[8];
        *(uint4*)&BT  [p*72 + l0]     = *(uint4*)&tbt[0];
        *(uint4*)&BT  [p*72 + l0 + 8] = *(uint4*)&tbt[8];
    }
    __syncthreads();

    int arow  = wave*16 + (lane & 15);        // A-frag row (output row band)
    int kof   = (lane >> 4) * 8;              // within-frag k offset
    int rbase = wave*16 + ((lane >> 4) << 2); // D-frag row base
    int cl    = lane & 15;                    // D-frag col within 16

    // ---- G = C·B^T --------------------------------------------------------
    f32x4 g[4];
    #pragma unroll
    for (int j = 0; j < 4; ++j) g[j] = (f32x4){0.f,0.f,0.f,0.f};
    #pragma unroll
    for (int k = 0; k < 2; ++k){
        bf16x8 a = *(const bf16x8*)&Cs[arow*72 + k*32 + kof];
        #pragma unroll
        for (int j = 0; j < 4; ++j){
            bf16x8 bb = *(const bf16x8*)&Bs[(16*j + (lane&15))*72 + k*32 + kof];
            g[j] = __builtin_amdgcn_mfma_f32_16x16x32_bf16(a, bb, g[j], 0, 0, 0);
        }
    }
    __syncthreads();   // all waves done reading Cs/Bs; region0 -> Mf

    // ---- M = tril(G * exp(cs[l]-cs[s])) into f32 LDS ----------------------
    #pragma unroll
    for (int j = 0; j < 4; ++j){
        #pragma unroll
        for (int r = 0; r < 4; ++r){
            int row = rbase + r, col = 16*j + cl;
            float m = 0.f;
            if (col <= row) m = g[j][r] * __expf(csh[row] - csh[col]);
            Mf[row*65 + col] = m;
        }
    }
    __syncthreads();

    // ---- Y_diag = M·Xd  (A = M bf16-converted, B = XdT) -------------------
    f32x4 y[4];
    #pragma unroll
    for (int j = 0; j < 4; ++j) y[j] = (f32x4){0.f,0.f,0.f,0.f};
    #pragma unroll
    for (int k = 0; k < 2; ++k){
        bf16x8 am;
        #pragma unroll
        for (int i = 0; i < 8; ++i)
            am[i] = (short)f2b(Mf[arow*65 + k*32 + kof + i]);
        #pragma unroll
        for (int j = 0; j < 4; ++j){
            bf16x8 bx = *(const bf16x8*)&XdT[(16*j + (lane&15))*72 + k*32 + kof];
            y[j] = __builtin_amdgcn_mfma_f32_16x16x32_bf16(am, bx, y[j], 0, 0, 0);
        }
    }
    #pragma unroll
    for (int j = 0; j < 4; ++j)
        #pragma unroll
        for (int r = 0; r < 4; ++r)
            y_g[(size_t)(r0 + rbase + r)*DIM + h*HEADDIM + 16*j + cl] = y[j][r];

    // ---- chunk_state[p][n] = sum_l WXdT[p][l] * BT[n][l] ------------------
    f32x4 st[4];
    #pragma unroll
    for (int j = 0; j < 4; ++j) st[j] = (f32x4){0.f,0.f,0.f,0.f};
    #pragma unroll
    for (int k = 0; k < 2; ++k){
        bf16x8 aw = *(const bf16x8*)&WXdT[arow*72 + k*32 + kof];
        #pragma unroll
        for (int j = 0; j < 4; ++j){
            bf16x8 bb = *(const bf16x8*)&BT[(16*j + (lane&15))*72 + k*32 + kof];
            st[j] = __builtin_amdgcn_mfma_f32_16x16x32_bf16(aw, bb, st[j], 0, 0, 0);
        }
    }
    #pragma unroll
    for (int j = 0; j < 4; ++j)
        #pragma unroll
        for (int r = 0; r < 4; ++r)
            cstate[(size_t)bid*4096 + (rbase + r)*64 + 16*j + cl] = st[j][r];
}

// ---------------------------------------------------------------------------
// K3: inter-chunk scan (in place: chunk_state -> states_in), emit final_state
__global__ __launch_bounds__(256) void k_scan(float* __restrict__ cstate,
        const float* __restrict__ css_g, float* __restrict__ fs_out){
    int bid = blockIdx.x;                  // b(2) * h(16) * tile(16)
    int tile = bid & 15, h = (bid >> 4) & 15, b = bid >> 8;
    int pn = tile*256 + threadIdx.x;
    float P = 0.f;
    for (int c = 0; c < NCHUNK; ++c){
        size_t base = (size_t)((b*NCHUNK + c)*HEADS + h);
        float e   = __expf(css_g[base*64 + 63]);
        float cur = cstate[base*4096 + pn];
        cstate[base*4096 + pn] = P;        // states_in for chunk c
        P = e*P + cur;
    }
    fs_out[(size_t)(b*HEADS + h)*4096 + pn] = P;
}

// ---------------------------------------------------------------------------
// K4 (MFMA): Y_off[l][p] = exp(cs[l]) * sum_n C[l][n] * S[p][n];  y += Y_off
__global__ __launch_bounds__(256) void k_yoff(const float* __restrict__ Cin,
        const float* __restrict__ cstate, const float* __restrict__ css_g,
        float* __restrict__ y_g){
    int bid = blockIdx.x;
    int h = bid & 15, c = (bid >> 4) & 63, b = bid >> 10;
    int tid = threadIdx.x;
    int lane = tid & 63, wave = tid >> 6;
    int r0 = b*SEQ + c*BLOCKL;
    __shared__ __align__(16) ushort Cs[64*72];   // C row-major [l][n]
    __shared__ __align__(16) ushort Ss[64*72];   // S row-major [p][n]
    __shared__ float cse[64];
    {
        int l  = tid >> 2;
        int c0 = (tid & 3) * 16;
        const float* cp = Cin    + (size_t)(r0 + l)*DIM + h*DSTATE + c0;
        const float* sp = cstate + (size_t)bid*4096 + l*64 + c0;
        ushort tc[16], ts[16];
        #pragma unroll
        for (int q = 0; q < 4; ++q){
            f32x4 vc = *(const f32x4*)(cp + q*4);
            f32x4 vs = *(const f32x4*)(sp + q*4);
            #pragma unroll
            for (int j = 0; j < 4; ++j){ tc[q*4+j] = f2b(vc[j]); ts[q*4+j] = f2b(vs[j]); }
        }
        *(uint4*)&Cs[l*72 + c0]     = *(uint4*)&tc[0];
        *(uint4*)&Cs[l*72 + c0 + 8] = *(uint4*)&tc[8];
        *(uint4*)&Ss[l*72 + c0]     = *(uint4*)&ts[0];
        *(uint4*)&Ss[l*72 + c0 + 8] = *(uint4*)&ts[8];
    }
    if (tid < 64) cse[tid] = __expf(css_g[(size_t)bid*64 + tid]);
    __syncthreads();

    int arow = wave*16 + (lane & 15);
    int kof  = (lane >> 4) * 8;
    f32x4 acc[4];
    #pragma unroll
    for (int j = 0; j < 4; ++j) acc[j] = (f32x4){0.f,0.f,0.f,0.f};
    #pragma unroll
    for (int k = 0; k < 2; ++k){
        bf16x8 a = *(const bf16x8*)&Cs[arow*72 + k*32 + kof];
        #pragma unroll
        for (int j = 0; j < 4; ++j){
            bf16x8 bb = *(const bf16x8*)&Ss[(16*j + (lane&15))*72 + k*32 + kof];
            acc[j] = __builtin_amdgcn_mfma_f32_16x16x32_bf16(a, bb, acc[j], 0, 0, 0);
        }
    }
    int rbase = wave*16 + ((lane >> 4) << 2);
    int cl = lane & 15;
    #pragma unroll
    for (int j = 0; j < 4; ++j)
        #pragma unroll
        for (int r = 0; r < 4; ++r){
            float e = cse[rbase + r];
            float* yp = y_g + (size_t)(r0 + rbase + r)*DIM + h*HEADDIM + 16*j + cl;
            *yp += e * acc[j][r];
        }
}

// ---------------------------------------------------------------------------
// K5: LayerNorm over dim, write bf16 yn
__global__ __launch_bounds__(256) void k_ln(const float* __restrict__ y_g,
        const float* __restrict__ scale, const float* __restrict__ bias,
        __hip_bfloat16* __restrict__ yn){
    int r = blockIdx.x, tid = threadIdx.x;
    const float* yp = y_g + (size_t)r*DIM;
    f32x4 v = *(const f32x4*)(yp + tid*4);
    float s1 = v.x + v.y + v.z + v.w;
    float s2 = v.x*v.x + v.y*v.y + v.z*v.z + v.w*v.w;
    #pragma unroll
    for (int m = 32; m > 0; m >>= 1){
        s1 += __shfl_xor(s1, m, 64);
        s2 += __shfl_xor(s2, m, 64);
    }
    __shared__ float w1[4], w2[4];
    int wv = tid >> 6;
    if ((tid & 63) == 0){ w1[wv] = s1; w2[wv] = s2; }
    __syncthreads();
    float S1 = w1[0]+w1[1]+w1[2]+w1[3];
    float S2 = w2[0]+w2[1]+w2[2]+w2[3];
    float mu  = S1 * (1.f/DIM);
    float var = S2 * (1.f/DIM) - mu*mu;
    float rstd = rsqrtf(var + 1e-6f);
    int d = tid*4;
    f32x4 sc = *(const f32x4*)(scale + d);
    f32x4 bi = *(const f32x4*)(bias + d);
    union { __hip_bfloat16 h[4]; short4 s4; } u;
    u.h[0] = __float2bfloat16((v.x - mu)*rstd*sc.x + bi.x);
    u.h[1] = __float2bfloat16((v.y - mu)*rstd*sc.y + bi.y);
    u.h[2] = __float2bfloat16((v.z - mu)*rstd*sc.z + bi.z);
    u.h[3] = __float2bfloat16((v.w - mu)*rstd*sc.w + bi.w);
    *(short4*)((short*)yn + (size_t)r*DIM + d) = u.s4;
}

// ---------------------------------------------------------------------------
// K5b: Wt[n][k] = bf16(W_out[k][n])
__global__ __launch_bounds__(256) void k_wt(const float* __restrict__ W,
        __hip_bfloat16* __restrict__ Wt){
    __shared__ float t[64][65];
    int kt = blockIdx.x >> 4, nt = blockIdx.x & 15;
    int tid = threadIdx.x;
    int lr = tid >> 4, lc4 = (tid & 15) * 4;
    #pragma unroll
    for (int q = 0; q < 4; ++q){
        int k = lr + q*16;
        *(f32x4*)&t[k][lc4] = *(const f32x4*)(W + (size_t)(kt*64 + k)*DIM + nt*64 + lc4);
    }
    __syncthreads();
    #pragma unroll
    for (int q = 0; q < 4; ++q){
        int n = lr + q*16;
        union { __hip_bfloat16 h[4]; short4 s4; } u;
        #pragma unroll
        for (int j = 0; j < 4; ++j) u.h[j] = __float2bfloat16(t[lc4+j][n]);
        *(short4*)((short*)Wt + (size_t)(nt*64 + n)*DIM + kt*64 + lc4) = u.s4;
    }
}

// ---------------------------------------------------------------------------
// K6: Out[m][n] = sum_k yn[m][k] * Wt[n][k]   (bf16 MFMA, f32 accum)
__global__ __launch_bounds__(256) void k_gemm(const __hip_bfloat16* __restrict__ A,
        const __hip_bfloat16* __restrict__ Bt, float* __restrict__ Out){
    __shared__ ushort As[128*32];
    __shared__ ushort Bsh[128*32];
    int bid = blockIdx.x;
    int bn = bid & 7, bm = bid >> 3;           // N/128 = 8, M/128 = 64
    int tid = threadIdx.x;
    int lane = tid & 63, wave = tid >> 6;
    int wr = wave >> 1, wc = wave & 1;
    f32x4 acc[4][4];
    #pragma unroll
    for (int i = 0; i < 4; ++i)
        #pragma unroll
        for (int j = 0; j < 4; ++j)
            acc[i][j] = (f32x4){0.f, 0.f, 0.f, 0.f};
    const ushort* Ag = (const ushort*)A  + (size_t)bm*128*1024;
    const ushort* Bg = (const ushort*)Bt + (size_t)bn*128*1024;
    int row0 = tid >> 2;
    int col0 = (tid & 3) * 8;
    for (int k0 = 0; k0 < 1024; k0 += 32){
        #pragma unroll
        for (int pass = 0; pass < 2; ++pass){
            int row = row0 + pass*64;
            *(uint4*)&As[row*32 + col0]  = *(const uint4*)(Ag + (size_t)row*1024 + k0 + col0);
            *(uint4*)&Bsh[row*32 + col0] = *(const uint4*)(Bg + (size_t)row*1024 + k0 + col0);
        }
        __syncthreads();
        bf16x8 af[4], bfr[4];
        #pragma unroll
        for (int i = 0; i < 4; ++i){
            int arow = wr*64 + i*16 + (lane & 15);
            af[i] = *(const bf16x8*)&As[arow*32 + ((lane >> 4) << 3)];
        }
        #pragma unroll
        for (int j = 0; j < 4; ++j){
            int brow = wc*64 + j*16 + (lane & 15);
            bfr[j] = *(const bf16x8*)&Bsh[brow*32 + ((lane >> 4) << 3)];
        }
        #pragma unroll
        for (int i = 0; i < 4; ++i)
            #pragma unroll
            for (int j = 0; j < 4; ++j)
                acc[i][j] = __builtin_amdgcn_mfma_f32_16x16x32_bf16(af[i], bfr[j], acc[i][j], 0, 0, 0);
        __syncthreads();
    }
    #pragma unroll
    for (int i = 0; i < 4; ++i){
        int m0 = bm*128 + wr*64 + i*16 + ((lane >> 4) << 2);
        #pragma unroll
        for (int j = 0; j < 4; ++j){
            int n = bn*128 + wc*64 + j*16 + (lane & 15);
            #pragma unroll
            for (int reg = 0; reg < 4; ++reg)
                Out[(size_t)(m0 + reg)*1024 + n] = acc[i][j][reg];
        }
    }
}

// ---------------------------------------------------------------------------
extern "C" void kernel_launch(void* const* d_in, const int* in_sizes, int n_in,
                              void* d_out, int out_size, void* d_ws, size_t ws_size,
                              hipStream_t stream){
    const float* X    = (const float*)d_in[0];
    const float* Bin  = (const float*)d_in[1];
    const float* Cin  = (const float*)d_in[2];
    const float* Wdt  = (const float*)d_in[3];
    const float* dtb  = (const float*)d_in[4];
    const float* alog = (const float*)d_in[5];
    const float* Wout = (const float*)d_in[6];
    const float* lns  = (const float*)d_in[7];
    const float* lnb  = (const float*)d_in[8];

    float* out = (float*)d_out;
    float* y_g = out;                       // reuse out region as y buffer
    float* fs_out = out + (size_t)ROWS*DIM; // final_state region

    float* dt_g   = (float*)d_ws;                       // 131072 f32
    float* dtA_g  = dt_g  + 131072;                     // 131072 f32
    float* css_g  = dtA_g + 131072;                     // 131072 f32
    float* cstate = css_g + 131072;                     // 8388608 f32
    __hip_bfloat16* yn = (__hip_bfloat16*)(cstate + 8388608);  // 8388608 bf16
    __hip_bfloat16* Wt = yn + (size_t)ROWS*DIM;                // 1048576 bf16

    k_dt   <<<ROWS,          256, 0, stream>>>(X, Wdt, dtb, alog, dt_g, dtA_g);
    k_chunk<<<BATCH*NCHUNK*HEADS, 256, 0, stream>>>(X, Bin, Cin, dt_g, dtA_g, y_g, cstate, css_g);
    k_scan <<<BATCH*HEADS*16, 256, 0, stream>>>(cstate, css_g, fs_out);
    k_yoff <<<BATCH*NCHUNK*HEADS, 256, 0, stream>>>(Cin, cstate, css_g, y_g);
    k_ln   <<<ROWS,          256, 0, stream>>>(y_g, lns, lnb, yn);
    k_wt   <<<256,           256, 0, stream>>>(Wout, Wt);
    k_gemm <<<512,           256, 0, stream>>>(yn, Wt, out);
}